// Round 1
// baseline (5262.534 us; speedup 1.0000x reference)
//
#include <hip/hip_runtime.h>

// LSTM: B=64, T=512, I=256, H=512, L=2, O=128. fp32 in/out, bf16 MFMA compute.
//
// Structure: 513 step-kernels (layer1 pipelined 1 step behind layer0), kernel
// boundaries provide cross-XCD coherence. Each step: 256 blocks = 2 layers x
// 4 batch-groups(16) x 32 h-col-groups(16). Block computes gates[16b x 64g]
// (i,f,g,o strips) with mfma_f32_16x16x32_bf16, K = [input | h] fused
// (768 for L0, 1024 for L1), weights pre-packed bf16 k-major in d_ws.
//
// ws layout (bytes):
//   0         x_bf16   [64][512][256] bf16   16,777,216
//   16777216  Wpack0   [2048][768]   bf16     3,145,728
//   19922944  Wpack1   [2048][1024]  bf16     4,194,304
//   24117248  h0 planes[2][64][512]  bf16       131,072
//   24248320  h1 planes[2][64][512]  bf16       131,072
//   24379392  c0       [64][512]     f32        131,072
//   24510464  c1       [64][512]     f32        131,072
//   total ~24.6 MB

#define B_  64
#define T_  512
#define I0_ 256
#define H_  512

typedef unsigned short ushort_t;
typedef __attribute__((ext_vector_type(8))) short   short8;   // 8 bf16 = 4 VGPR
typedef __attribute__((ext_vector_type(4))) float   float4v;  // MFMA C/D

__device__ __forceinline__ unsigned short f2bf(float f) {
    unsigned int u = __builtin_bit_cast(unsigned int, f);
    u += 0x7fffu + ((u >> 16) & 1u);           // RTNE
    return (unsigned short)(u >> 16);
}

// ---- prologue: x fp32 -> bf16 -------------------------------------------
__global__ void conv_x(const float* __restrict__ x, ushort_t* __restrict__ xb) {
    size_t i = ((size_t)blockIdx.x * 256 + threadIdx.x) * 4;
    float4 v = *(const float4*)(x + i);
    ushort4 o;
    o.x = f2bf(v.x); o.y = f2bf(v.y); o.z = f2bf(v.z); o.w = f2bf(v.w);
    *(ushort4*)(xb + i) = o;
}

// ---- prologue: pack [W_ih | W_hh] -> bf16, rows grouped per col-group ----
// packed row p = n*64 + strip*16 + jj  ->  gate row g = strip*512 + n*16 + jj
__global__ void pack_w(const float* __restrict__ wih0, const float* __restrict__ whh0,
                       const float* __restrict__ wih1, const float* __restrict__ whh1,
                       ushort_t* __restrict__ wp0, ushort_t* __restrict__ wp1) {
    int p = blockIdx.x;
    int layer = p >> 11;
    int row = p & 2047;
    int n = row >> 6, rem = row & 63;
    int st = rem >> 4, jj = rem & 15;
    int g = st * 512 + n * 16 + jj;
    if (layer == 0) {
        for (int k = threadIdx.x; k < 768; k += 256) {
            float v = (k < 256) ? wih0[(size_t)g * 256 + k]
                                : whh0[(size_t)g * 512 + (k - 256)];
            wp0[(size_t)row * 768 + k] = f2bf(v);
        }
    } else {
        for (int k = threadIdx.x; k < 1024; k += 256) {
            float v = (k < 512) ? wih1[(size_t)g * 512 + k]
                                : whh1[(size_t)g * 512 + (k - 512)];
            wp1[(size_t)row * 1024 + k] = f2bf(v);
        }
    }
}

// ---- prologue: zero h planes + c ----------------------------------------
__global__ void zero_ws(uint4* p) {
    p[(size_t)blockIdx.x * 256 + threadIdx.x] = uint4{0, 0, 0, 0};
}

// ---- per-timestep kernel -------------------------------------------------
// global step s in [0,512]. layer0 computes t=s (s<512); layer1 t=s-1 (s>=1).
// h0: layer0 reads plane (s+1)&1, writes plane s&1.
// h1: layer1 reads plane s&1,     writes plane (s+1)&1.
// layer1's input = h_seq0[s-1] = h0 plane (s-1)&1 == (s+1)&1.
__global__ __launch_bounds__(256) void step_kernel(
    const ushort_t* __restrict__ xbf,
    const ushort_t* __restrict__ wp0,
    const ushort_t* __restrict__ wp1,
    ushort_t* __restrict__ h0,
    ushort_t* __restrict__ h1,
    float* __restrict__ c0,
    float* __restrict__ c1,
    const float* __restrict__ bi0, const float* __restrict__ bh0,
    const float* __restrict__ bi1, const float* __restrict__ bh1,
    float* __restrict__ dout,
    int s)
{
    const int blk = blockIdx.x;
    const int layer = blk >> 7;
    if (layer == 0 && s >= 512) return;
    if (layer == 1 && s == 0) return;
    const int id = blk & 127;
    const int m = id >> 5;      // batch group
    const int n = id & 31;      // h-col group
    const int b0 = m * 16;
    const int t = layer ? (s - 1) : s;

    const int lane = threadIdx.x & 63;
    const int wv   = threadIdx.x >> 6;   // gate strip: 0=i 1=f 2=g 3=o
    const int lr   = lane & 15;          // A row (batch) / B col (gate)
    const int lq   = lane >> 4;          // quad -> k sub-offset

    const int rp   = (s + 1) & 1;
    const int wpar = s & 1;

    float4v acc = {0.f, 0.f, 0.f, 0.f};

    if (layer == 0) {
        const ushort_t* h0r = h0 + rp * (B_ * H_);
        const ushort_t* ap  = xbf + ((size_t)(b0 + lr)) * (T_ * I0_) + (size_t)s * I0_ + lq * 8;
        const ushort_t* bp  = wp0 + ((size_t)(n * 64 + wv * 16 + lr)) * 768 + lq * 8;
        #pragma unroll
        for (int kc = 0; kc < 8; ++kc) {
            short8 a = *(const short8*)(ap + kc * 32);
            short8 b = *(const short8*)(bp + kc * 32);
            acc = __builtin_amdgcn_mfma_f32_16x16x32_bf16(a, b, acc, 0, 0, 0);
        }
        const ushort_t* ap2 = h0r + (b0 + lr) * H_ + lq * 8;
        const ushort_t* bp2 = bp + 256;
        #pragma unroll
        for (int kc = 0; kc < 16; ++kc) {
            short8 a = *(const short8*)(ap2 + kc * 32);
            short8 b = *(const short8*)(bp2 + kc * 32);
            acc = __builtin_amdgcn_mfma_f32_16x16x32_bf16(a, b, acc, 0, 0, 0);
        }
    } else {
        const ushort_t* hxr = h0 + rp * (B_ * H_);     // h_seq0[t]
        const ushort_t* h1r = h1 + wpar * (B_ * H_);   // h1[t-1]
        const ushort_t* ap  = hxr + (b0 + lr) * H_ + lq * 8;
        const ushort_t* bp  = wp1 + ((size_t)(n * 64 + wv * 16 + lr)) * 1024 + lq * 8;
        #pragma unroll
        for (int kc = 0; kc < 16; ++kc) {
            short8 a = *(const short8*)(ap + kc * 32);
            short8 b = *(const short8*)(bp + kc * 32);
            acc = __builtin_amdgcn_mfma_f32_16x16x32_bf16(a, b, acc, 0, 0, 0);
        }
        const ushort_t* ap2 = h1r + (b0 + lr) * H_ + lq * 8;
        const ushort_t* bp2 = bp + 512;
        #pragma unroll
        for (int kc = 0; kc < 16; ++kc) {
            short8 a = *(const short8*)(ap2 + kc * 32);
            short8 b = *(const short8*)(bp2 + kc * 32);
            acc = __builtin_amdgcn_mfma_f32_16x16x32_bf16(a, b, acc, 0, 0, 0);
        }
    }

    // exchange i/f/g/o strips across waves.
    // D layout (16x16x32): col = lane&15, row = (lane>>4)*4 + reg
    __shared__ float xch[4][16][16];
    #pragma unroll
    for (int r = 0; r < 4; ++r) xch[wv][lq * 4 + r][lr] = acc[r];
    __syncthreads();

    const int tid = threadIdx.x;
    const int bb_ = tid >> 4;       // local batch 0..15
    const int j   = tid & 15;       // local h col 0..15
    const int col = n * 16 + j;     // h index 0..511
    const int bb  = b0 + bb_;

    float iv = xch[0][bb_][j];
    float fv = xch[1][bb_][j];
    float gv = xch[2][bb_][j];
    float ov = xch[3][bb_][j];

    const float* bi = layer ? bi1 : bi0;
    const float* bh = layer ? bh1 : bh0;
    iv += bi[col]        + bh[col];
    fv += bi[512 + col]  + bh[512 + col];
    gv += bi[1024 + col] + bh[1024 + col];
    ov += bi[1536 + col] + bh[1536 + col];

    float* cbuf = layer ? c1 : c0;
    float cold = cbuf[bb * H_ + col];
    float ig = 1.f / (1.f + __expf(-iv));
    float fg = 1.f / (1.f + __expf(-fv));
    float og = 1.f / (1.f + __expf(-ov));
    float gg = tanhf(gv);
    float cn = fg * cold + ig * gg;
    float hn = og * tanhf(cn);
    cbuf[bb * H_ + col] = cn;

    ushort_t hb = f2bf(hn);
    if (layer == 0) {
        (h0 + wpar * (B_ * H_))[bb * H_ + col] = hb;
    } else {
        (h1 + rp * (B_ * H_))[bb * H_ + col] = hb;
        // lstm_out[b][t][h], fp32
        dout[8192 + ((size_t)bb * T_ + t) * H_ + col] = hn;
    }
    if (t == 511) {
        dout[16785408 + (size_t)layer * (B_ * H_) + bb * H_ + col] = hn;  // hidden
        dout[16850944 + (size_t)layer * (B_ * H_) + bb * H_ + col] = cn;  // cell
    }
}

// ---- final projection: out = h1T @ W_out^T + b_out -----------------------
__global__ void out_gemm(const float* __restrict__ h1T, const float* __restrict__ wout,
                         const float* __restrict__ bout, float* __restrict__ out) {
    int b = blockIdx.x, o = threadIdx.x;
    const float* hr = h1T + (size_t)b * 512;
    const float* wr = wout + (size_t)o * 512;
    float acc = bout[o];
    #pragma unroll 8
    for (int k = 0; k < 512; ++k) acc += hr[k] * wr[k];
    out[b * 128 + o] = acc;
}

extern "C" void kernel_launch(void* const* d_in, const int* in_sizes, int n_in,
                              void* d_out, int out_size, void* d_ws, size_t ws_size,
                              hipStream_t stream)
{
    const float* x    = (const float*)d_in[0];
    const float* wih0 = (const float*)d_in[1];
    const float* whh0 = (const float*)d_in[2];
    const float* bih0 = (const float*)d_in[3];
    const float* bhh0 = (const float*)d_in[4];
    const float* wih1 = (const float*)d_in[5];
    const float* whh1 = (const float*)d_in[6];
    const float* bih1 = (const float*)d_in[7];
    const float* bhh1 = (const float*)d_in[8];
    const float* wout = (const float*)d_in[9];
    const float* bout = (const float*)d_in[10];
    float* out = (float*)d_out;

    char* ws = (char*)d_ws;
    ushort_t* xbf = (ushort_t*)(ws);
    ushort_t* wp0 = (ushort_t*)(ws + 16777216);
    ushort_t* wp1 = (ushort_t*)(ws + 19922944);
    ushort_t* h0  = (ushort_t*)(ws + 24117248);
    ushort_t* h1  = (ushort_t*)(ws + 24248320);
    float*    c0  = (float*)   (ws + 24379392);
    float*    c1  = (float*)   (ws + 24510464);

    conv_x<<<8192, 256, 0, stream>>>(x, xbf);                  // 8192*256*4 = 8,388,608
    pack_w<<<4096, 256, 0, stream>>>(wih0, whh0, wih1, whh1, wp0, wp1);
    zero_ws<<<128, 256, 0, stream>>>((uint4*)(ws + 24117248)); // 524,288 B of h/c state

    for (int s = 0; s < 513; ++s) {
        step_kernel<<<256, 256, 0, stream>>>(xbf, wp0, wp1, h0, h1, c0, c1,
                                             bih0, bhh0, bih1, bhh1, out, s);
    }
    // hidden[1] = h1T lives at float offset 16785408 + 64*512
    out_gemm<<<64, 128, 0, stream>>>(out + 16785408 + B_ * H_, wout, bout, out);
}